// Round 3
// baseline (634.687 us; speedup 1.0000x reference)
//
#include <hip/hip_runtime.h>

#define BB 16
#define TT 512
#define DD 64
#define HH 128
#define SS 100
#define MSZ 20
#define NROW (BB*TT)      // 8192
#define FOURH 512

__device__ __forceinline__ float frcp(float x){ return __builtin_amdgcn_rcpf(x); }
__device__ __forceinline__ float sigmoidf_(float x){
    return frcp(1.0f + __expf(-x));
}
__device__ __forceinline__ float tanhf_(float x){
    float t = __expf(2.0f * x);
    return 1.0f - 2.0f * frcp(t + 1.0f);   // rcp(inf)=0 -> saturates to +/-1
}

// ---------------- kernel A: xw = inputs @ lstm_kernel + bias ----------------
__global__ __launch_bounds__(512) void k_xw(const float* __restrict__ inp,
        const float* __restrict__ Wk, const float* __restrict__ bias,
        float* __restrict__ xw){
    __shared__ float in_s[8 * DD];
    int tid = threadIdx.x;
    int r0 = blockIdx.x * 8;
    in_s[tid] = inp[(size_t)r0 * DD + tid];
    __syncthreads();
    int j = tid;
    float wreg[DD];
    #pragma unroll
    for (int d = 0; d < DD; ++d) wreg[d] = Wk[d * FOURH + j];
    float bv = bias[j];
    const float4* in4 = reinterpret_cast<const float4*>(in_s);
    #pragma unroll
    for (int r = 0; r < 8; ++r){
        float acc = bv;
        #pragma unroll
        for (int q = 0; q < DD/4; ++q){
            float4 iv = in4[r*(DD/4) + q];
            acc = fmaf(iv.x, wreg[4*q+0], acc);
            acc = fmaf(iv.y, wreg[4*q+1], acc);
            acc = fmaf(iv.z, wreg[4*q+2], acc);
            acc = fmaf(iv.w, wreg[4*q+3], acc);
        }
        xw[(size_t)(r0 + r) * FOURH + j] = acc;
    }
}

// ---------------- kernel B: LSTM scan, one block per batch element ----------
// 1024 threads: thread j owns neuron k=j>>3 and h-chunk s=j&7 (16 of 128 h).
// Computes 16-MAC partials for all 4 gates of k (4 independent FMA chains),
// reduces over the 8 chunk lanes via shfl_xor butterfly (xor1/xor2 = DPP on
// the VALU pipe; xor4 = one ds_swizzle per gate). All 8 lanes then hold
// bit-identical gate sums -> activations + c/h update computed redundantly,
// no LDS exchange, ONE barrier per step. h lives in LDS with a 16->20 dword
// chunk stride so the 8 distinct ds_read_b128 addrs cover all 32 banks.
__global__ __launch_bounds__(1024, 4) void k_scan(const float* __restrict__ xw,
        const float* __restrict__ Rk, float* __restrict__ ctrl){
    __shared__ float hbuf[2][160];   // chunk s at dwords [20s, 20s+16)
    int j = threadIdx.x;
    int b = blockIdx.x;
    int k = j >> 3;        // neuron 0..127
    int s = j & 7;         // h-chunk 0..7 (16 values each)
    // Rk fragment: rows [16s, 16s+16), cols {k, 128+k, 256+k, 384+k}
    float rk[64];
    #pragma unroll
    for (int g = 0; g < 4; ++g)
        #pragma unroll
        for (int kk = 0; kk < 16; ++kk)
            rk[g*16 + kk] = Rk[(s*16 + kk) * FOURH + g*128 + k];
    if (j < 160){ hbuf[0][j] = 0.0f; hbuf[1][j] = 0.0f; }
    float c = 0.0f;
    const float* xb = xw + (size_t)b * TT * FOURH;
    bool ldx = (s < 4);
    int xcol = s*128 + k;                       // gate-s column of neuron k
    float xcur = ldx ? xb[xcol] : 0.0f;         // t = 0
    float xnxt = ldx ? xb[FOURH + xcol] : 0.0f; // t = 1
    __syncthreads();
    int p = 0;
    for (int t = 0; t < TT; ++t){
        const float4* h4 = reinterpret_cast<const float4*>(&hbuf[p][s*20]);
        float4 hv0 = h4[0], hv1 = h4[1], hv2 = h4[2], hv3 = h4[3];
        float a0 = (s == 0) ? xcur : 0.0f;
        float a1 = (s == 1) ? xcur : 0.0f;
        float a2 = (s == 2) ? xcur : 0.0f;
        float a3 = (s == 3) ? xcur : 0.0f;
        #define QFMA(hvq, q) \
            a0 = fmaf(hvq.x, rk[0*16+4*q+0], a0); a0 = fmaf(hvq.y, rk[0*16+4*q+1], a0); \
            a0 = fmaf(hvq.z, rk[0*16+4*q+2], a0); a0 = fmaf(hvq.w, rk[0*16+4*q+3], a0); \
            a1 = fmaf(hvq.x, rk[1*16+4*q+0], a1); a1 = fmaf(hvq.y, rk[1*16+4*q+1], a1); \
            a1 = fmaf(hvq.z, rk[1*16+4*q+2], a1); a1 = fmaf(hvq.w, rk[1*16+4*q+3], a1); \
            a2 = fmaf(hvq.x, rk[2*16+4*q+0], a2); a2 = fmaf(hvq.y, rk[2*16+4*q+1], a2); \
            a2 = fmaf(hvq.z, rk[2*16+4*q+2], a2); a2 = fmaf(hvq.w, rk[2*16+4*q+3], a2); \
            a3 = fmaf(hvq.x, rk[3*16+4*q+0], a3); a3 = fmaf(hvq.y, rk[3*16+4*q+1], a3); \
            a3 = fmaf(hvq.z, rk[3*16+4*q+2], a3); a3 = fmaf(hvq.w, rk[3*16+4*q+3], a3);
        QFMA(hv0, 0) QFMA(hv1, 1) QFMA(hv2, 2) QFMA(hv3, 3)
        #undef QFMA
        // butterfly over the 8 chunk lanes (lanes j^1, j^2 via DPP; j^4 via swizzle)
        a0 += __shfl_xor(a0, 1); a0 += __shfl_xor(a0, 2); a0 += __shfl_xor(a0, 4);
        a1 += __shfl_xor(a1, 1); a1 += __shfl_xor(a1, 2); a1 += __shfl_xor(a1, 4);
        a2 += __shfl_xor(a2, 1); a2 += __shfl_xor(a2, 2); a2 += __shfl_xor(a2, 4);
        a3 += __shfl_xor(a3, 1); a3 += __shfl_xor(a3, 2); a3 += __shfl_xor(a3, 4);
        float ig = sigmoidf_(a0);
        float fg = sigmoidf_(a1);
        float gg = tanhf_(a2);
        float og = sigmoidf_(a3);
        c = fg * c + ig * gg;
        float h = og * tanhf_(c);
        if (s == 0) hbuf[p ^ 1][(k >> 4)*20 + (k & 15)] = h;
        if (s == 1) ctrl[((size_t)b * TT + t) * HH + k] = h;
        xcur = xnxt;
        if (t + 2 < TT) xnxt = ldx ? xb[(size_t)(t + 2) * FOURH + xcol] : 0.0f;
        p ^= 1;
        __syncthreads();
    }
}

// ---------------- kernel C: proj = ctrl @ [8 heads' W] + biases; also copies
// ctrl into out[:, 0:128] ----------------------------------------------------
__global__ __launch_bounds__(320) void k_proj(const float* __restrict__ ctrl,
        const float* __restrict__ rWk, const float* __restrict__ rbk,
        const float* __restrict__ wWk, const float* __restrict__ wbk,
        const float* __restrict__ wWe, const float* __restrict__ wbe,
        const float* __restrict__ wWa, const float* __restrict__ wba,
        float* __restrict__ proj, float* __restrict__ out){
    __shared__ float cs[16 * HH];
    int tid = threadIdx.x;
    int r0 = blockIdx.x * 16;
    for (int idx = tid; idx < 16 * HH; idx += 320){
        float v = ctrl[(size_t)r0 * HH + idx];
        cs[idx] = v;
        int r = idx >> 7, k = idx & 127;
        out[(size_t)(r0 + r) * 168 + k] = v;
    }
    __syncthreads();
    int j = tid % 160;
    int rh = tid / 160;
    int p = j / MSZ, m = j % MSZ;
    const float* Wp; const float* bp;
    switch (p){
        case 0:  Wp = rWk;            bp = rbk;        break;
        case 1:  Wp = rWk + HH*MSZ;   bp = rbk + MSZ;  break;
        case 2:  Wp = wWk;            bp = wbk;        break;
        case 3:  Wp = wWk + HH*MSZ;   bp = wbk + MSZ;  break;
        case 4:  Wp = wWe;            bp = wbe;        break;
        case 5:  Wp = wWe + HH*MSZ;   bp = wbe + MSZ;  break;
        case 6:  Wp = wWa;            bp = wba;        break;
        default: Wp = wWa + HH*MSZ;   bp = wba + MSZ;  break;
    }
    float wv[HH];
    #pragma unroll
    for (int k = 0; k < HH; ++k) wv[k] = Wp[k * MSZ + m];
    float bv = bp[m];
    #pragma unroll
    for (int r = 0; r < 8; ++r){
        int row = rh * 8 + r;
        float acc = bv;
        const float4* c4 = reinterpret_cast<const float4*>(cs + row * HH);
        #pragma unroll
        for (int q = 0; q < HH/4; ++q){
            float4 cv = c4[q];
            acc = fmaf(cv.x, wv[4*q+0], acc);
            acc = fmaf(cv.y, wv[4*q+1], acc);
            acc = fmaf(cv.z, wv[4*q+2], acc);
            acc = fmaf(cv.w, wv[4*q+3], acc);
        }
        proj[(size_t)(r0 + row) * 160 + j] = acc;
    }
}

// ---------------- kernel D: heads, one block per (b,t) ----------------------
__device__ __forceinline__ float blocksum128(float v, float* red){
    #pragma unroll
    for (int o = 1; o < 64; o <<= 1) v += __shfl_xor(v, o, 64);
    int tid = threadIdx.x;
    if ((tid & 63) == 0) red[tid >> 6] = v;
    __syncthreads();
    float s = red[0] + red[1];
    __syncthreads();
    return s;
}

__global__ __launch_bounds__(128) void k_heads(const float* __restrict__ proj,
        const float* __restrict__ memory, float* __restrict__ out,
        float* __restrict__ outmem){
    __shared__ float mem0[SS * MSZ];
    __shared__ float rn[SS];
    __shared__ float khat[4][MSZ];
    __shared__ float ea[4][MSZ];
    __shared__ float wrd[2][SS];
    __shared__ float red[2];
    __shared__ float pz[160];
    int tid = threadIdx.x;
    int bt = blockIdx.x;
    for (int idx = tid; idx < SS * MSZ; idx += 128) mem0[idx] = memory[idx];
    for (int idx = tid; idx < 160; idx += 128) pz[idx] = proj[(size_t)bt * 160 + idx];
    __syncthreads();
    if (tid < SS){
        float s2 = 0.0f;
        #pragma unroll
        for (int m = 0; m < MSZ; ++m){ float v = mem0[tid*MSZ + m]; s2 = fmaf(v, v, s2); }
        rn[tid] = rsqrtf(fmaxf(s2, 1e-12f));
    }
    {   // 4 key heads: softmax over 20 then l2-normalize; plus e/a heads
        int g = tid >> 5, lm = tid & 31;
        float z = (lm < MSZ) ? pz[g*MSZ + lm] : 0.0f;
        float e = (lm < MSZ) ? __expf(z) : 0.0f;
        float ssum = e;
        #pragma unroll
        for (int o = 1; o < 32; o <<= 1) ssum += __shfl_xor(ssum, o, 32);
        float kv = e / ssum;
        float qs = kv * kv;
        #pragma unroll
        for (int o = 1; o < 32; o <<= 1) qs += __shfl_xor(qs, o, 32);
        float kn = kv * rsqrtf(fmaxf(qs, 1e-12f));
        if (lm < MSZ) khat[g][lm] = kn;
        float z2 = (lm < MSZ) ? pz[80 + g*MSZ + lm] : 0.0f;
        float v2 = (g < 2) ? sigmoidf_(z2) : z2;
        if (lm < MSZ) ea[g][lm] = v2;
    }
    __syncthreads();
    bool act = tid < SS;
    int s = tid;
    float d0 = 0.f, d1 = 0.f, dw = 0.f;
    if (act){
        #pragma unroll
        for (int m = 0; m < MSZ; ++m){
            float mv = mem0[s*MSZ + m];
            d0 = fmaf(khat[0][m], mv, d0);
            d1 = fmaf(khat[1][m], mv, d1);
            dw = fmaf(khat[2][m], mv, dw);
        }
    }
    float rns = act ? rn[s] : 0.0f;
    float e0 = act ? __expf(-rns * d0) : 0.0f;
    float e1 = act ? __expf(-rns * d1) : 0.0f;
    float ew = act ? __expf(-rns * dw) : 0.0f;
    float sum0 = blocksum128(e0, red);
    float sum1 = blocksum128(e1, red);
    float sumw = blocksum128(ew, red);
    if (act){ wrd[0][s] = e0 / sum0; wrd[1][s] = e1 / sum1; }
    float w0 = ew / sumw;
    float m1[MSZ];
    float n1 = 0.f, dkw = 0.f;
    if (act){
        #pragma unroll
        for (int m = 0; m < MSZ; ++m){
            float mv = mem0[s*MSZ + m];
            float v = fmaf(-w0 * ea[0][m], mv, mv);   // (1 - w0*e0)*mem
            v = fmaf(w0, ea[2][m], v);                // + w0*a0
            m1[m] = v;
            n1 = fmaf(v, v, n1);
            dkw = fmaf(khat[3][m], v, dkw);
        }
    }
    float rn1 = rsqrtf(fmaxf(n1, 1e-12f));
    float e1w = act ? __expf(-rn1 * dkw) : 0.0f;
    float sum1w = blocksum128(e1w, red);
    float w1 = e1w / sum1w;
    if (act){
        float buf[MSZ];
        #pragma unroll
        for (int m = 0; m < MSZ; ++m){
            float v = m1[m];
            float v2 = fmaf(-w1 * ea[1][m], v, v);
            v2 = fmaf(w1, ea[3][m], v2);
            buf[m] = v2;
        }
        float4* dst = reinterpret_cast<float4*>(outmem + ((size_t)bt * SS + s) * MSZ);
        #pragma unroll
        for (int q = 0; q < MSZ/4; ++q)
            dst[q] = make_float4(buf[4*q], buf[4*q+1], buf[4*q+2], buf[4*q+3]);
    }
    __syncthreads();
    if (tid < 2 * MSZ){
        int hd = tid / MSZ, m = tid % MSZ;
        float acc = 0.0f;
        for (int s2 = 0; s2 < SS; ++s2)
            acc = fmaf(wrd[hd][s2], mem0[s2*MSZ + m], acc);
        out[(size_t)bt * 168 + 128 + hd*MSZ + m] = acc;
    }
}

extern "C" void kernel_launch(void* const* d_in, const int* in_sizes, int n_in,
                              void* d_out, int out_size, void* d_ws, size_t ws_size,
                              hipStream_t stream){
    const float* inputs = (const float*)d_in[0];
    const float* memory = (const float*)d_in[1];
    const float* Wk     = (const float*)d_in[2];
    const float* Rk     = (const float*)d_in[3];
    const float* bias   = (const float*)d_in[4];
    const float* rWk    = (const float*)d_in[5];
    const float* rbk    = (const float*)d_in[6];
    const float* wWk    = (const float*)d_in[7];
    const float* wbk    = (const float*)d_in[8];
    const float* wWe    = (const float*)d_in[9];
    const float* wbe    = (const float*)d_in[10];
    const float* wWa    = (const float*)d_in[11];
    const float* wba    = (const float*)d_in[12];

    float* out    = (float*)d_out;
    float* outmem = out + (size_t)NROW * 168;
    // xw scratch aliases the (dead until k_heads) mem-output region: 4.19M of 16.38M floats
    float* xw   = outmem;
    float* ctrl = (float*)d_ws;
    float* proj = ctrl + (size_t)NROW * HH;

    k_xw  <<<NROW/8,  512, 0, stream>>>(inputs, Wk, bias, xw);
    k_scan<<<BB,     1024, 0, stream>>>(xw, Rk, ctrl);
    k_proj<<<NROW/16, 320, 0, stream>>>(ctrl, rWk, rbk, wWk, wbk, wWe, wbe, wWa, wba, proj, out);
    k_heads<<<NROW,   128, 0, stream>>>(proj, memory, out, outmem);
}

// Round 4
// 563.772 us; speedup vs baseline: 1.1258x; 1.1258x over previous
//
#include <hip/hip_runtime.h>
#include <hip/hip_bf16.h>

#define BB 16
#define TT 512
#define DD 64
#define HH 128
#define SS 100
#define MSZ 20
#define NROW (BB*TT)      // 8192
#define FOURH 512

typedef __attribute__((ext_vector_type(8))) short bh8;   // 8 bf16 in 4 VGPRs
typedef __attribute__((ext_vector_type(4))) float fv4;   // MFMA accumulator

__device__ __forceinline__ float frcp(float x){ return __builtin_amdgcn_rcpf(x); }
__device__ __forceinline__ float sigmoidf_(float x){
    return frcp(1.0f + __expf(-x));
}
__device__ __forceinline__ float tanhf_(float x){
    float t = __expf(2.0f * x);
    return 1.0f - 2.0f * frcp(t + 1.0f);   // rcp(inf)=0 -> saturates to +/-1
}
__device__ __forceinline__ unsigned short f2bf(float f){
    __hip_bfloat16 h = __float2bfloat16(f);   // RNE
    union { __hip_bfloat16 b; unsigned short u; } cv; cv.b = h;
    return cv.u;
}

// ---------------- kernel A: xw = inputs @ lstm_kernel + bias ----------------
__global__ __launch_bounds__(512) void k_xw(const float* __restrict__ inp,
        const float* __restrict__ Wk, const float* __restrict__ bias,
        float* __restrict__ xw){
    __shared__ float in_s[8 * DD];
    int tid = threadIdx.x;
    int r0 = blockIdx.x * 8;
    in_s[tid] = inp[(size_t)r0 * DD + tid];
    __syncthreads();
    int j = tid;
    float wreg[DD];
    #pragma unroll
    for (int d = 0; d < DD; ++d) wreg[d] = Wk[d * FOURH + j];
    float bv = bias[j];
    const float4* in4 = reinterpret_cast<const float4*>(in_s);
    #pragma unroll
    for (int r = 0; r < 8; ++r){
        float acc = bv;
        #pragma unroll
        for (int q = 0; q < DD/4; ++q){
            float4 iv = in4[r*(DD/4) + q];
            acc = fmaf(iv.x, wreg[4*q+0], acc);
            acc = fmaf(iv.y, wreg[4*q+1], acc);
            acc = fmaf(iv.z, wreg[4*q+2], acc);
            acc = fmaf(iv.w, wreg[4*q+3], acc);
        }
        xw[(size_t)(r0 + r) * FOURH + j] = acc;
    }
}

// ---------------- kernel B: LSTM scan via MFMA, ONE block, all 16 batches ---
// Per step: (16x128 h, bf16) @ (128x512 Rk, bf16 in VGPRs) via 16x16x32 MFMA.
// 8 waves; wave w owns N-tiles at cols {g*128 + 16w .. +15} for g=i,f,g,o ->
// each lane's 4 accumulators hold the 4 gates of its (batch,neuron): the
// whole LSTM cell update is lane-local. C-init = xw (fused add). h is stored
// bf16 in LDS [batch][128] with byte-XOR swizzle ((batch&7)<<4) -> A-frags
// are 4x ds_read_b128, ~2-way conflicts max. One barrier/step, double-buffer.
// c stays fp32 in regs; ctrl written fp32. Only the h->matvec path is bf16.
__global__ __launch_bounds__(512, 2) void k_scan(const float* __restrict__ xw,
        const float* __restrict__ Rk, float* __restrict__ ctrl){
    __shared__ __align__(16) unsigned short hb[2][2048];  // 2 x [16 batch][128 neuron] bf16
    const int tid = threadIdx.x;
    const int w  = tid >> 6;     // wave 0..7
    const int l  = tid & 63;
    const int q  = l >> 4;       // k-group 0..3
    const int lo = l & 15;
    // zero both h buffers (8192 B = 512 * 16 B)
    {
        uint4* z4 = (uint4*)&hb[0][0];
        z4[tid] = make_uint4(0u,0u,0u,0u);
    }
    // ---- pack Rk into B-fragments (bf16), resident in VGPRs ----
    // B-frag for gate Ti, K-step kk: lane l supplies B[k=32kk+8q+j][col=128Ti+16w+lo]
    bh8 bf[4][4];
    #pragma unroll
    for (int Ti = 0; Ti < 4; ++Ti){
        const int col = Ti*128 + w*16 + lo;
        #pragma unroll
        for (int kk = 0; kk < 4; ++kk){
            union { unsigned short us[8]; bh8 v; } u;
            #pragma unroll
            for (int j = 0; j < 8; ++j)
                u.us[j] = f2bf(Rk[(size_t)(kk*32 + q*8 + j)*FOURH + col]);
            bf[Ti][kk] = u.v;
        }
    }
    // ---- per-lane state: c for 4 batches (4q+r), xw regs ----
    float c[4] = {0.f, 0.f, 0.f, 0.f};
    float xc[16], xn[16];
    #pragma unroll
    for (int Ti = 0; Ti < 4; ++Ti)
        #pragma unroll
        for (int r = 0; r < 4; ++r)
            xc[Ti*4+r] = xw[((size_t)(4*q+r)*TT + 0)*FOURH + Ti*128 + w*16 + lo];
    __syncthreads();
    int p = 0;
    const int swz = (lo & 7) << 4;
    for (int t = 0; t < TT; ++t){
        // A-fragments: lane l = batch lo, neurons 32kk+8q..+7 (16 B contiguous, swizzled)
        const char* hbase = (const char*)&hb[0][0] + p*4096 + lo*256;
        union { uint4 u; bh8 v; } a0, a1, a2, a3;
        a0.u = *(const uint4*)(hbase + ((  0 + 16*q) ^ swz));
        a1.u = *(const uint4*)(hbase + (( 64 + 16*q) ^ swz));
        a2.u = *(const uint4*)(hbase + ((128 + 16*q) ^ swz));
        a3.u = *(const uint4*)(hbase + ((192 + 16*q) ^ swz));
        // C-init = xw[t]  (C layout: batch=(l>>4)*4+r, col=l&15 -> matches load)
        fv4 ac0 = {xc[0],  xc[1],  xc[2],  xc[3]};
        fv4 ac1 = {xc[4],  xc[5],  xc[6],  xc[7]};
        fv4 ac2 = {xc[8],  xc[9],  xc[10], xc[11]};
        fv4 ac3 = {xc[12], xc[13], xc[14], xc[15]};
        // prefetch next step's xw (independent; hides under MFMA)
        const int tn = (t+1 < TT) ? t+1 : t;
        #pragma unroll
        for (int Ti = 0; Ti < 4; ++Ti)
            #pragma unroll
            for (int r = 0; r < 4; ++r)
                xn[Ti*4+r] = xw[((size_t)(4*q+r)*TT + tn)*FOURH + Ti*128 + w*16 + lo];
        // z = h @ Rk + xw  (4 gates x K-chain of 4)
        ac0 = __builtin_amdgcn_mfma_f32_16x16x32_bf16(a0.v, bf[0][0], ac0, 0,0,0);
        ac1 = __builtin_amdgcn_mfma_f32_16x16x32_bf16(a0.v, bf[1][0], ac1, 0,0,0);
        ac2 = __builtin_amdgcn_mfma_f32_16x16x32_bf16(a0.v, bf[2][0], ac2, 0,0,0);
        ac3 = __builtin_amdgcn_mfma_f32_16x16x32_bf16(a0.v, bf[3][0], ac3, 0,0,0);
        ac0 = __builtin_amdgcn_mfma_f32_16x16x32_bf16(a1.v, bf[0][1], ac0, 0,0,0);
        ac1 = __builtin_amdgcn_mfma_f32_16x16x32_bf16(a1.v, bf[1][1], ac1, 0,0,0);
        ac2 = __builtin_amdgcn_mfma_f32_16x16x32_bf16(a1.v, bf[2][1], ac2, 0,0,0);
        ac3 = __builtin_amdgcn_mfma_f32_16x16x32_bf16(a1.v, bf[3][1], ac3, 0,0,0);
        ac0 = __builtin_amdgcn_mfma_f32_16x16x32_bf16(a2.v, bf[0][2], ac0, 0,0,0);
        ac1 = __builtin_amdgcn_mfma_f32_16x16x32_bf16(a2.v, bf[1][2], ac1, 0,0,0);
        ac2 = __builtin_amdgcn_mfma_f32_16x16x32_bf16(a2.v, bf[2][2], ac2, 0,0,0);
        ac3 = __builtin_amdgcn_mfma_f32_16x16x32_bf16(a2.v, bf[3][2], ac3, 0,0,0);
        ac0 = __builtin_amdgcn_mfma_f32_16x16x32_bf16(a3.v, bf[0][3], ac0, 0,0,0);
        ac1 = __builtin_amdgcn_mfma_f32_16x16x32_bf16(a3.v, bf[1][3], ac1, 0,0,0);
        ac2 = __builtin_amdgcn_mfma_f32_16x16x32_bf16(a3.v, bf[2][3], ac2, 0,0,0);
        ac3 = __builtin_amdgcn_mfma_f32_16x16x32_bf16(a3.v, bf[3][3], ac3, 0,0,0);
        // lane-local LSTM cell update for 4 (batch=4q+r, neuron=16w+lo) pairs
        #pragma unroll
        for (int r = 0; r < 4; ++r){
            float ig = sigmoidf_(ac0[r]);
            float fg = sigmoidf_(ac1[r]);
            float gg = tanhf_   (ac2[r]);
            float og = sigmoidf_(ac3[r]);
            c[r] = fg * c[r] + ig * gg;
            float h = og * tanhf_(c[r]);
            const int B = 4*q + r;
            ctrl[((size_t)B*TT + t)*HH + w*16 + lo] = h;
            *(unsigned short*)((char*)&hb[0][0] + (p^1)*4096 + B*256
                               + ((32*w + 2*lo) ^ ((B & 7) << 4))) = f2bf(h);
        }
        #pragma unroll
        for (int i = 0; i < 16; ++i) xc[i] = xn[i];
        p ^= 1;
        __syncthreads();
    }
}

// ---------------- kernel C: proj = ctrl @ [8 heads' W] + biases; also copies
// ctrl into out[:, 0:128] ----------------------------------------------------
__global__ __launch_bounds__(320) void k_proj(const float* __restrict__ ctrl,
        const float* __restrict__ rWk, const float* __restrict__ rbk,
        const float* __restrict__ wWk, const float* __restrict__ wbk,
        const float* __restrict__ wWe, const float* __restrict__ wbe,
        const float* __restrict__ wWa, const float* __restrict__ wba,
        float* __restrict__ proj, float* __restrict__ out){
    __shared__ float cs[16 * HH];
    int tid = threadIdx.x;
    int r0 = blockIdx.x * 16;
    for (int idx = tid; idx < 16 * HH; idx += 320){
        float v = ctrl[(size_t)r0 * HH + idx];
        cs[idx] = v;
        int r = idx >> 7, k = idx & 127;
        out[(size_t)(r0 + r) * 168 + k] = v;
    }
    __syncthreads();
    int j = tid % 160;
    int rh = tid / 160;
    int p = j / MSZ, m = j % MSZ;
    const float* Wp; const float* bp;
    switch (p){
        case 0:  Wp = rWk;            bp = rbk;        break;
        case 1:  Wp = rWk + HH*MSZ;   bp = rbk + MSZ;  break;
        case 2:  Wp = wWk;            bp = wbk;        break;
        case 3:  Wp = wWk + HH*MSZ;   bp = wbk + MSZ;  break;
        case 4:  Wp = wWe;            bp = wbe;        break;
        case 5:  Wp = wWe + HH*MSZ;   bp = wbe + MSZ;  break;
        case 6:  Wp = wWa;            bp = wba;        break;
        default: Wp = wWa + HH*MSZ;   bp = wba + MSZ;  break;
    }
    float wv[HH];
    #pragma unroll
    for (int k = 0; k < HH; ++k) wv[k] = Wp[k * MSZ + m];
    float bv = bp[m];
    #pragma unroll
    for (int r = 0; r < 8; ++r){
        int row = rh * 8 + r;
        float acc = bv;
        const float4* c4 = reinterpret_cast<const float4*>(cs + row * HH);
        #pragma unroll
        for (int q = 0; q < HH/4; ++q){
            float4 cv = c4[q];
            acc = fmaf(cv.x, wv[4*q+0], acc);
            acc = fmaf(cv.y, wv[4*q+1], acc);
            acc = fmaf(cv.z, wv[4*q+2], acc);
            acc = fmaf(cv.w, wv[4*q+3], acc);
        }
        proj[(size_t)(r0 + row) * 160 + j] = acc;
    }
}

// ---------------- kernel D: heads, one block per (b,t) ----------------------
__device__ __forceinline__ float blocksum128(float v, float* red){
    #pragma unroll
    for (int o = 1; o < 64; o <<= 1) v += __shfl_xor(v, o, 64);
    int tid = threadIdx.x;
    if ((tid & 63) == 0) red[tid >> 6] = v;
    __syncthreads();
    float s = red[0] + red[1];
    __syncthreads();
    return s;
}

__global__ __launch_bounds__(128) void k_heads(const float* __restrict__ proj,
        const float* __restrict__ memory, float* __restrict__ out,
        float* __restrict__ outmem){
    __shared__ float mem0[SS * MSZ];
    __shared__ float rn[SS];
    __shared__ float khat[4][MSZ];
    __shared__ float ea[4][MSZ];
    __shared__ float wrd[2][SS];
    __shared__ float red[2];
    __shared__ float pz[160];
    int tid = threadIdx.x;
    int bt = blockIdx.x;
    for (int idx = tid; idx < SS * MSZ; idx += 128) mem0[idx] = memory[idx];
    for (int idx = tid; idx < 160; idx += 128) pz[idx] = proj[(size_t)bt * 160 + idx];
    __syncthreads();
    if (tid < SS){
        float s2 = 0.0f;
        #pragma unroll
        for (int m = 0; m < MSZ; ++m){ float v = mem0[tid*MSZ + m]; s2 = fmaf(v, v, s2); }
        rn[tid] = rsqrtf(fmaxf(s2, 1e-12f));
    }
    {   // 4 key heads: softmax over 20 then l2-normalize; plus e/a heads
        int g = tid >> 5, lm = tid & 31;
        float z = (lm < MSZ) ? pz[g*MSZ + lm] : 0.0f;
        float e = (lm < MSZ) ? __expf(z) : 0.0f;
        float ssum = e;
        #pragma unroll
        for (int o = 1; o < 32; o <<= 1) ssum += __shfl_xor(ssum, o, 32);
        float kv = e / ssum;
        float qs = kv * kv;
        #pragma unroll
        for (int o = 1; o < 32; o <<= 1) qs += __shfl_xor(qs, o, 32);
        float kn = kv * rsqrtf(fmaxf(qs, 1e-12f));
        if (lm < MSZ) khat[g][lm] = kn;
        float z2 = (lm < MSZ) ? pz[80 + g*MSZ + lm] : 0.0f;
        float v2 = (g < 2) ? sigmoidf_(z2) : z2;
        if (lm < MSZ) ea[g][lm] = v2;
    }
    __syncthreads();
    bool act = tid < SS;
    int s = tid;
    float d0 = 0.f, d1 = 0.f, dw = 0.f;
    if (act){
        #pragma unroll
        for (int m = 0; m < MSZ; ++m){
            float mv = mem0[s*MSZ + m];
            d0 = fmaf(khat[0][m], mv, d0);
            d1 = fmaf(khat[1][m], mv, d1);
            dw = fmaf(khat[2][m], mv, dw);
        }
    }
    float rns = act ? rn[s] : 0.0f;
    float e0 = act ? __expf(-rns * d0) : 0.0f;
    float e1 = act ? __expf(-rns * d1) : 0.0f;
    float ew = act ? __expf(-rns * dw) : 0.0f;
    float sum0 = blocksum128(e0, red);
    float sum1 = blocksum128(e1, red);
    float sumw = blocksum128(ew, red);
    if (act){ wrd[0][s] = e0 / sum0; wrd[1][s] = e1 / sum1; }
    float w0 = ew / sumw;
    float m1[MSZ];
    float n1 = 0.f, dkw = 0.f;
    if (act){
        #pragma unroll
        for (int m = 0; m < MSZ; ++m){
            float mv = mem0[s*MSZ + m];
            float v = fmaf(-w0 * ea[0][m], mv, mv);   // (1 - w0*e0)*mem
            v = fmaf(w0, ea[2][m], v);                // + w0*a0
            m1[m] = v;
            n1 = fmaf(v, v, n1);
            dkw = fmaf(khat[3][m], v, dkw);
        }
    }
    float rn1 = rsqrtf(fmaxf(n1, 1e-12f));
    float e1w = act ? __expf(-rn1 * dkw) : 0.0f;
    float sum1w = blocksum128(e1w, red);
    float w1 = e1w / sum1w;
    if (act){
        float buf[MSZ];
        #pragma unroll
        for (int m = 0; m < MSZ; ++m){
            float v = m1[m];
            float v2 = fmaf(-w1 * ea[1][m], v, v);
            v2 = fmaf(w1, ea[3][m], v2);
            buf[m] = v2;
        }
        float4* dst = reinterpret_cast<float4*>(outmem + ((size_t)bt * SS + s) * MSZ);
        #pragma unroll
        for (int q = 0; q < MSZ/4; ++q)
            dst[q] = make_float4(buf[4*q], buf[4*q+1], buf[4*q+2], buf[4*q+3]);
    }
    __syncthreads();
    if (tid < 2 * MSZ){
        int hd = tid / MSZ, m = tid % MSZ;
        float acc = 0.0f;
        for (int s2 = 0; s2 < SS; ++s2)
            acc = fmaf(wrd[hd][s2], mem0[s2*MSZ + m], acc);
        out[(size_t)bt * 168 + 128 + hd*MSZ + m] = acc;
    }
}

extern "C" void kernel_launch(void* const* d_in, const int* in_sizes, int n_in,
                              void* d_out, int out_size, void* d_ws, size_t ws_size,
                              hipStream_t stream){
    const float* inputs = (const float*)d_in[0];
    const float* memory = (const float*)d_in[1];
    const float* Wk     = (const float*)d_in[2];
    const float* Rk     = (const float*)d_in[3];
    const float* bias   = (const float*)d_in[4];
    const float* rWk    = (const float*)d_in[5];
    const float* rbk    = (const float*)d_in[6];
    const float* wWk    = (const float*)d_in[7];
    const float* wbk    = (const float*)d_in[8];
    const float* wWe    = (const float*)d_in[9];
    const float* wbe    = (const float*)d_in[10];
    const float* wWa    = (const float*)d_in[11];
    const float* wba    = (const float*)d_in[12];

    float* out    = (float*)d_out;
    float* outmem = out + (size_t)NROW * 168;
    // xw scratch aliases the (dead until k_heads) mem-output region
    float* xw   = outmem;
    float* ctrl = (float*)d_ws;
    float* proj = ctrl + (size_t)NROW * HH;

    k_xw  <<<NROW/8,  512, 0, stream>>>(inputs, Wk, bias, xw);
    k_scan<<<1,       512, 0, stream>>>(xw, Rk, ctrl);
    k_proj<<<NROW/16, 320, 0, stream>>>(ctrl, rWk, rbk, wWk, wbk, wWe, wbe, wWa, wba, proj, out);
    k_heads<<<NROW,   128, 0, stream>>>(proj, memory, out, outmem);
}

// Round 5
// 330.372 us; speedup vs baseline: 1.9211x; 1.7065x over previous
//
#include <hip/hip_runtime.h>
#include <hip/hip_bf16.h>

#define BB 16
#define TT 512
#define DD 64
#define HH 128
#define SS 100
#define MSZ 20
#define NROW (BB*TT)      // 8192
#define FOURH 512

typedef __attribute__((ext_vector_type(8))) short bh8;   // 8 bf16 in 4 VGPRs
typedef __attribute__((ext_vector_type(4))) float fv4;   // MFMA accumulator

__device__ __forceinline__ float frcp(float x){ return __builtin_amdgcn_rcpf(x); }
__device__ __forceinline__ float sigmoidf_(float x){
    return frcp(1.0f + __expf(-x));
}
__device__ __forceinline__ float tanhf_(float x){
    float t = __expf(2.0f * x);
    return 1.0f - 2.0f * frcp(t + 1.0f);   // rcp(inf)=0 -> saturates to +/-1
}
__device__ __forceinline__ unsigned short f2bf(float f){
    __hip_bfloat16 h = __float2bfloat16(f);   // RNE
    union { __hip_bfloat16 b; unsigned short u; } cv; cv.b = h;
    return cv.u;
}

// ---------------- kernel A: xw = inputs @ lstm_kernel + bias ----------------
__global__ __launch_bounds__(512) void k_xw(const float* __restrict__ inp,
        const float* __restrict__ Wk, const float* __restrict__ bias,
        float* __restrict__ xw){
    __shared__ float in_s[8 * DD];
    int tid = threadIdx.x;
    int r0 = blockIdx.x * 8;
    in_s[tid] = inp[(size_t)r0 * DD + tid];
    __syncthreads();
    int j = tid;
    float wreg[DD];
    #pragma unroll
    for (int d = 0; d < DD; ++d) wreg[d] = Wk[d * FOURH + j];
    float bv = bias[j];
    const float4* in4 = reinterpret_cast<const float4*>(in_s);
    #pragma unroll
    for (int r = 0; r < 8; ++r){
        float acc = bv;
        #pragma unroll
        for (int q = 0; q < DD/4; ++q){
            float4 iv = in4[r*(DD/4) + q];
            acc = fmaf(iv.x, wreg[4*q+0], acc);
            acc = fmaf(iv.y, wreg[4*q+1], acc);
            acc = fmaf(iv.z, wreg[4*q+2], acc);
            acc = fmaf(iv.w, wreg[4*q+3], acc);
        }
        xw[(size_t)(r0 + r) * FOURH + j] = acc;
    }
}

// ---------------- kernel B: LSTM scan via MFMA, ONE block PER BATCH ---------
// Block b = batch b (16 blocks -> 16 CUs). Per step: (1x128 h) @ (128x512 Rk)
// as 16x16x32 MFMA with A-rows 1..15 held at zero (LDS zero-init, only row 0
// written). 8 waves; wave w owns cols {Ti*128 + 16w + lo}, Ti=0..3 -> lane
// lo<16 (q==0, reg 0) holds all 4 gates of neuron 16w+lo: cell update is
// lane-local. xw added post-MFMA (scalar, 4 loads on 16 lanes). h stored bf16
// in row 0 of a double-buffered, XOR-swizzled LDS tile; one barrier/step.
__global__ __launch_bounds__(512, 2) void k_scan(const float* __restrict__ xw,
        const float* __restrict__ Rk, float* __restrict__ ctrl){
    __shared__ __align__(16) unsigned short hb[2][2048];  // 2 x [16 rows][128 k] bf16
    const int tid = threadIdx.x;
    const int b  = blockIdx.x;   // batch
    const int w  = tid >> 6;     // wave 0..7
    const int l  = tid & 63;
    const int q  = l >> 4;       // k-group 0..3
    const int lo = l & 15;       // A-row / C-col
    { uint4* z4 = (uint4*)&hb[0][0]; z4[tid] = make_uint4(0u,0u,0u,0u); }
    // ---- Rk B-fragments (bf16), resident in VGPRs: 64 VGPRs ----
    bh8 bf[4][4];
    #pragma unroll
    for (int Ti = 0; Ti < 4; ++Ti){
        const int col = Ti*128 + w*16 + lo;
        #pragma unroll
        for (int kk = 0; kk < 4; ++kk){
            union { unsigned short us[8]; bh8 v; } u;
            #pragma unroll
            for (int j = 0; j < 8; ++j)
                u.us[j] = f2bf(Rk[(size_t)(kk*32 + q*8 + j)*FOURH + col]);
            bf[Ti][kk] = u.v;
        }
    }
    const bool upd = (q == 0);          // lanes 0..15: own neuron n = 16w+lo
    const int  n   = w*16 + lo;
    const float* xb = xw + (size_t)b * TT * FOURH;
    float c0 = 0.0f;
    float xc0=0.f, xc1=0.f, xc2=0.f, xc3=0.f;
    if (upd){
        xc0 = xb[0*128 + n]; xc1 = xb[1*128 + n];
        xc2 = xb[2*128 + n]; xc3 = xb[3*128 + n];
    }
    const int swz = (lo & 7) << 4;
    __syncthreads();
    int p = 0;
    for (int t = 0; t < TT; ++t){
        const char* hbase = (const char*)&hb[0][0] + p*4096 + lo*256;
        union { uint4 u; bh8 v; } a0, a1, a2, a3;
        a0.u = *(const uint4*)(hbase + ((q*16 +   0) ^ swz));
        a1.u = *(const uint4*)(hbase + ((q*16 +  64) ^ swz));
        a2.u = *(const uint4*)(hbase + ((q*16 + 128) ^ swz));
        a3.u = *(const uint4*)(hbase + ((q*16 + 192) ^ swz));
        // prefetch next step's xw (independent of MFMA)
        const int tn = (t+1 < TT) ? t+1 : t;
        float xn0=0.f, xn1=0.f, xn2=0.f, xn3=0.f;
        if (upd){
            const float* xr = xb + (size_t)tn * FOURH;
            xn0 = xr[0*128 + n]; xn1 = xr[1*128 + n];
            xn2 = xr[2*128 + n]; xn3 = xr[3*128 + n];
        }
        fv4 z0 = {0.f,0.f,0.f,0.f}, z1 = z0, z2 = z0, z3 = z0;
        z0 = __builtin_amdgcn_mfma_f32_16x16x32_bf16(a0.v, bf[0][0], z0, 0,0,0);
        z1 = __builtin_amdgcn_mfma_f32_16x16x32_bf16(a0.v, bf[1][0], z1, 0,0,0);
        z2 = __builtin_amdgcn_mfma_f32_16x16x32_bf16(a0.v, bf[2][0], z2, 0,0,0);
        z3 = __builtin_amdgcn_mfma_f32_16x16x32_bf16(a0.v, bf[3][0], z3, 0,0,0);
        z0 = __builtin_amdgcn_mfma_f32_16x16x32_bf16(a1.v, bf[0][1], z0, 0,0,0);
        z1 = __builtin_amdgcn_mfma_f32_16x16x32_bf16(a1.v, bf[1][1], z1, 0,0,0);
        z2 = __builtin_amdgcn_mfma_f32_16x16x32_bf16(a1.v, bf[2][1], z2, 0,0,0);
        z3 = __builtin_amdgcn_mfma_f32_16x16x32_bf16(a1.v, bf[3][1], z3, 0,0,0);
        z0 = __builtin_amdgcn_mfma_f32_16x16x32_bf16(a2.v, bf[0][2], z0, 0,0,0);
        z1 = __builtin_amdgcn_mfma_f32_16x16x32_bf16(a2.v, bf[1][2], z1, 0,0,0);
        z2 = __builtin_amdgcn_mfma_f32_16x16x32_bf16(a2.v, bf[2][2], z2, 0,0,0);
        z3 = __builtin_amdgcn_mfma_f32_16x16x32_bf16(a2.v, bf[3][2], z3, 0,0,0);
        z0 = __builtin_amdgcn_mfma_f32_16x16x32_bf16(a3.v, bf[0][3], z0, 0,0,0);
        z1 = __builtin_amdgcn_mfma_f32_16x16x32_bf16(a3.v, bf[1][3], z1, 0,0,0);
        z2 = __builtin_amdgcn_mfma_f32_16x16x32_bf16(a3.v, bf[2][3], z2, 0,0,0);
        z3 = __builtin_amdgcn_mfma_f32_16x16x32_bf16(a3.v, bf[3][3], z3, 0,0,0);
        if (upd){
            float zi = z0[0] + xc0;
            float zf = z1[0] + xc1;
            float zg = z2[0] + xc2;
            float zo = z3[0] + xc3;
            float ig = sigmoidf_(zi);
            float fg = sigmoidf_(zf);
            float gg = tanhf_   (zg);
            float og = sigmoidf_(zo);
            c0 = fg * c0 + ig * gg;
            float h = og * tanhf_(c0);
            ctrl[((size_t)b*TT + t)*HH + n] = h;
            *(unsigned short*)((char*)&hb[0][0] + (p^1)*4096 + 2*n) = f2bf(h);
            xc0 = xn0; xc1 = xn1; xc2 = xn2; xc3 = xn3;
        }
        p ^= 1;
        __syncthreads();
    }
}

// ---------------- kernel C: proj = ctrl @ [8 heads' W] + biases; also copies
// ctrl into out[:, 0:128] ----------------------------------------------------
__global__ __launch_bounds__(320) void k_proj(const float* __restrict__ ctrl,
        const float* __restrict__ rWk, const float* __restrict__ rbk,
        const float* __restrict__ wWk, const float* __restrict__ wbk,
        const float* __restrict__ wWe, const float* __restrict__ wbe,
        const float* __restrict__ wWa, const float* __restrict__ wba,
        float* __restrict__ proj, float* __restrict__ out){
    __shared__ float cs[16 * HH];
    int tid = threadIdx.x;
    int r0 = blockIdx.x * 16;
    for (int idx = tid; idx < 16 * HH; idx += 320){
        float v = ctrl[(size_t)r0 * HH + idx];
        cs[idx] = v;
        int r = idx >> 7, k = idx & 127;
        out[(size_t)(r0 + r) * 168 + k] = v;
    }
    __syncthreads();
    int j = tid % 160;
    int rh = tid / 160;
    int p = j / MSZ, m = j % MSZ;
    const float* Wp; const float* bp;
    switch (p){
        case 0:  Wp = rWk;            bp = rbk;        break;
        case 1:  Wp = rWk + HH*MSZ;   bp = rbk + MSZ;  break;
        case 2:  Wp = wWk;            bp = wbk;        break;
        case 3:  Wp = wWk + HH*MSZ;   bp = wbk + MSZ;  break;
        case 4:  Wp = wWe;            bp = wbe;        break;
        case 5:  Wp = wWe + HH*MSZ;   bp = wbe + MSZ;  break;
        case 6:  Wp = wWa;            bp = wba;        break;
        default: Wp = wWa + HH*MSZ;   bp = wba + MSZ;  break;
    }
    float wv[HH];
    #pragma unroll
    for (int k = 0; k < HH; ++k) wv[k] = Wp[k * MSZ + m];
    float bv = bp[m];
    #pragma unroll
    for (int r = 0; r < 8; ++r){
        int row = rh * 8 + r;
        float acc = bv;
        const float4* c4 = reinterpret_cast<const float4*>(cs + row * HH);
        #pragma unroll
        for (int q = 0; q < HH/4; ++q){
            float4 cv = c4[q];
            acc = fmaf(cv.x, wv[4*q+0], acc);
            acc = fmaf(cv.y, wv[4*q+1], acc);
            acc = fmaf(cv.z, wv[4*q+2], acc);
            acc = fmaf(cv.w, wv[4*q+3], acc);
        }
        proj[(size_t)(r0 + row) * 160 + j] = acc;
    }
}

// ---------------- kernel D: heads, one block per (b,t) ----------------------
__device__ __forceinline__ float blocksum128(float v, float* red){
    #pragma unroll
    for (int o = 1; o < 64; o <<= 1) v += __shfl_xor(v, o, 64);
    int tid = threadIdx.x;
    if ((tid & 63) == 0) red[tid >> 6] = v;
    __syncthreads();
    float s = red[0] + red[1];
    __syncthreads();
    return s;
}

__global__ __launch_bounds__(128) void k_heads(const float* __restrict__ proj,
        const float* __restrict__ memory, float* __restrict__ out,
        float* __restrict__ outmem){
    __shared__ float mem0[SS * MSZ];
    __shared__ float rn[SS];
    __shared__ float khat[4][MSZ];
    __shared__ float ea[4][MSZ];
    __shared__ float wrd[2][SS];
    __shared__ float red[2];
    __shared__ float pz[160];
    int tid = threadIdx.x;
    int bt = blockIdx.x;
    for (int idx = tid; idx < SS * MSZ; idx += 128) mem0[idx] = memory[idx];
    for (int idx = tid; idx < 160; idx += 128) pz[idx] = proj[(size_t)bt * 160 + idx];
    __syncthreads();
    if (tid < SS){
        float s2 = 0.0f;
        #pragma unroll
        for (int m = 0; m < MSZ; ++m){ float v = mem0[tid*MSZ + m]; s2 = fmaf(v, v, s2); }
        rn[tid] = rsqrtf(fmaxf(s2, 1e-12f));
    }
    {   // 4 key heads: softmax over 20 then l2-normalize; plus e/a heads
        int g = tid >> 5, lm = tid & 31;
        float z = (lm < MSZ) ? pz[g*MSZ + lm] : 0.0f;
        float e = (lm < MSZ) ? __expf(z) : 0.0f;
        float ssum = e;
        #pragma unroll
        for (int o = 1; o < 32; o <<= 1) ssum += __shfl_xor(ssum, o, 32);
        float kv = e / ssum;
        float qs = kv * kv;
        #pragma unroll
        for (int o = 1; o < 32; o <<= 1) qs += __shfl_xor(qs, o, 32);
        float kn = kv * rsqrtf(fmaxf(qs, 1e-12f));
        if (lm < MSZ) khat[g][lm] = kn;
        float z2 = (lm < MSZ) ? pz[80 + g*MSZ + lm] : 0.0f;
        float v2 = (g < 2) ? sigmoidf_(z2) : z2;
        if (lm < MSZ) ea[g][lm] = v2;
    }
    __syncthreads();
    bool act = tid < SS;
    int s = tid;
    float d0 = 0.f, d1 = 0.f, dw = 0.f;
    if (act){
        #pragma unroll
        for (int m = 0; m < MSZ; ++m){
            float mv = mem0[s*MSZ + m];
            d0 = fmaf(khat[0][m], mv, d0);
            d1 = fmaf(khat[1][m], mv, d1);
            dw = fmaf(khat[2][m], mv, dw);
        }
    }
    float rns = act ? rn[s] : 0.0f;
    float e0 = act ? __expf(-rns * d0) : 0.0f;
    float e1 = act ? __expf(-rns * d1) : 0.0f;
    float ew = act ? __expf(-rns * dw) : 0.0f;
    float sum0 = blocksum128(e0, red);
    float sum1 = blocksum128(e1, red);
    float sumw = blocksum128(ew, red);
    if (act){ wrd[0][s] = e0 / sum0; wrd[1][s] = e1 / sum1; }
    float w0 = ew / sumw;
    float m1[MSZ];
    float n1 = 0.f, dkw = 0.f;
    if (act){
        #pragma unroll
        for (int m = 0; m < MSZ; ++m){
            float mv = mem0[s*MSZ + m];
            float v = fmaf(-w0 * ea[0][m], mv, mv);   // (1 - w0*e0)*mem
            v = fmaf(w0, ea[2][m], v);                // + w0*a0
            m1[m] = v;
            n1 = fmaf(v, v, n1);
            dkw = fmaf(khat[3][m], v, dkw);
        }
    }
    float rn1 = rsqrtf(fmaxf(n1, 1e-12f));
    float e1w = act ? __expf(-rn1 * dkw) : 0.0f;
    float sum1w = blocksum128(e1w, red);
    float w1 = e1w / sum1w;
    if (act){
        float buf[MSZ];
        #pragma unroll
        for (int m = 0; m < MSZ; ++m){
            float v = m1[m];
            float v2 = fmaf(-w1 * ea[1][m], v, v);
            v2 = fmaf(w1, ea[3][m], v2);
            buf[m] = v2;
        }
        float4* dst = reinterpret_cast<float4*>(outmem + ((size_t)bt * SS + s) * MSZ);
        #pragma unroll
        for (int q = 0; q < MSZ/4; ++q)
            dst[q] = make_float4(buf[4*q], buf[4*q+1], buf[4*q+2], buf[4*q+3]);
    }
    __syncthreads();
    if (tid < 2 * MSZ){
        int hd = tid / MSZ, m = tid % MSZ;
        float acc = 0.0f;
        for (int s2 = 0; s2 < SS; ++s2)
            acc = fmaf(wrd[hd][s2], mem0[s2*MSZ + m], acc);
        out[(size_t)bt * 168 + 128 + hd*MSZ + m] = acc;
    }
}

extern "C" void kernel_launch(void* const* d_in, const int* in_sizes, int n_in,
                              void* d_out, int out_size, void* d_ws, size_t ws_size,
                              hipStream_t stream){
    const float* inputs = (const float*)d_in[0];
    const float* memory = (const float*)d_in[1];
    const float* Wk     = (const float*)d_in[2];
    const float* Rk     = (const float*)d_in[3];
    const float* bias   = (const float*)d_in[4];
    const float* rWk    = (const float*)d_in[5];
    const float* rbk    = (const float*)d_in[6];
    const float* wWk    = (const float*)d_in[7];
    const float* wbk    = (const float*)d_in[8];
    const float* wWe    = (const float*)d_in[9];
    const float* wbe    = (const float*)d_in[10];
    const float* wWa    = (const float*)d_in[11];
    const float* wba    = (const float*)d_in[12];

    float* out    = (float*)d_out;
    float* outmem = out + (size_t)NROW * 168;
    // xw scratch aliases the (dead until k_heads) mem-output region
    float* xw   = outmem;
    float* ctrl = (float*)d_ws;
    float* proj = ctrl + (size_t)NROW * HH;

    k_xw  <<<NROW/8,  512, 0, stream>>>(inputs, Wk, bias, xw);
    k_scan<<<BB,      512, 0, stream>>>(xw, Rk, ctrl);
    k_proj<<<NROW/16, 320, 0, stream>>>(ctrl, rWk, rbk, wWk, wbk, wWe, wbe, wWa, wba, proj, out);
    k_heads<<<NROW,   128, 0, stream>>>(proj, memory, out, outmem);
}